// Round 6
// baseline (224.527 us; speedup 1.0000x reference)
//
#include <hip/hip_runtime.h>
#include <math.h>

// B=2048, N=8192, fp32. Fused kernel, one block per row, 256 threads.
// R6: register-pressure endgame. R1-R5 all allocated 60-64 VGPR against ~100
// live values, yet WRITE_SIZE showed zero scratch traffic -> the compiler was
// NOT spilling, it was REMATERIALIZING r in the epilogue by re-reading
// yp/yt from L2/L3 (invisible in FETCH_SIZE). The kernel was secretly a
// multi-pass-over-memory kernel; that's why DPP/store/launch_bounds fixes
// were all null. Fix: stage r in LDS (32KB/block) so it exists ONCE outside
// registers; hist+epilogue read it back via ds_read_b128 (~256cy/block).
// Barriers between write and reads prevent store-to-load forwarding from
// re-inflating register pressure. Also: non-temporal output stores so the
// 64MB write stream stops evicting L3-resident inputs across iterations.
#define N_COLS 8192
#define BLOCK  256
#define NW     4                    // waves per block
#define F4PT   (N_COLS / BLOCK / 4) // float4 groups per thread = 8
#define NBINS  1024
#define BPL    (NBINS / 64)         // 16 bins per lane in the Newton wave

// d_out[0] must be zeroed every call (harness re-poisons to 0xAA).
__global__ void zero_out_kernel(float* out) {
    if (threadIdx.x == 0 && blockIdx.x == 0) out[0] = 0.0f;
}

// Canonical gfx9 wave64 reduce via DPP: row_shr 1/2/4/8, row_bcast15 (rows
// 1,3), row_bcast31 (rows 2,3); total lands in lane 63, readlane -> uniform.
__device__ __forceinline__ float wave64_sum_dpp(float x) {
    union fi { float f; int i; };
    fi v, t; v.f = x;
    t.i = __builtin_amdgcn_update_dpp(0, v.i, 0x111, 0xf, 0xf, true); v.f += t.f;
    t.i = __builtin_amdgcn_update_dpp(0, v.i, 0x112, 0xf, 0xf, true); v.f += t.f;
    t.i = __builtin_amdgcn_update_dpp(0, v.i, 0x114, 0xf, 0xf, true); v.f += t.f;
    t.i = __builtin_amdgcn_update_dpp(0, v.i, 0x118, 0xf, 0xf, true); v.f += t.f;
    t.i = __builtin_amdgcn_update_dpp(0, v.i, 0x142, 0xa, 0xf, true); v.f += t.f;
    t.i = __builtin_amdgcn_update_dpp(0, v.i, 0x143, 0xc, 0xf, true); v.f += t.f;
    v.i = __builtin_amdgcn_readlane(v.i, 63);
    return v.f;
}

__device__ __forceinline__ float wave64_max_dpp(float x) {
    union fi { float f; int i; };
    fi v, t; v.f = x;   // residuals >= 0, so bound_ctrl identity-0 is safe
    t.i = __builtin_amdgcn_update_dpp(0, v.i, 0x111, 0xf, 0xf, true); v.f = fmaxf(v.f, t.f);
    t.i = __builtin_amdgcn_update_dpp(0, v.i, 0x112, 0xf, 0xf, true); v.f = fmaxf(v.f, t.f);
    t.i = __builtin_amdgcn_update_dpp(0, v.i, 0x114, 0xf, 0xf, true); v.f = fmaxf(v.f, t.f);
    t.i = __builtin_amdgcn_update_dpp(0, v.i, 0x118, 0xf, 0xf, true); v.f = fmaxf(v.f, t.f);
    t.i = __builtin_amdgcn_update_dpp(0, v.i, 0x142, 0xa, 0xf, true); v.f = fmaxf(v.f, t.f);
    t.i = __builtin_amdgcn_update_dpp(0, v.i, 0x143, 0xc, 0xf, true); v.f = fmaxf(v.f, t.f);
    v.i = __builtin_amdgcn_readlane(v.i, 63);
    return v.f;
}

__global__ __launch_bounds__(BLOCK) void custom_loss_kernel(
        const float* __restrict__ y_pred,
        const float* __restrict__ y_true,
        const float* __restrict__ Lambda,
        float* __restrict__ out,      // out[0]=loss, out[1..]=updated_Lambda
        float inv_total) {
    __shared__ float4 s_r[N_COLS / 4];       // 32KB residual stage
    __shared__ unsigned int s_hist[NBINS];   // 4KB count histogram
    __shared__ float s_wmax[NW];
    __shared__ float s_part[NW];
    __shared__ float s_bcast[2];             // {beta, inv_qmax}

    const int row  = blockIdx.x;
    const int tid  = threadIdx.x;
    const int lane = tid & 63;
    const int wid  = tid >> 6;
    const size_t base = (size_t)row * N_COLS;
    const float4* yp4 = (const float4*)(y_pred + base);  // rows are 32KB-aligned
    const float4* yt4 = (const float4*)(y_true + base);

    // ---- pass 1: load once, residuals -> LDS, local max ----
    float rmax = 0.0f;
    #pragma unroll
    for (int j = 0; j < F4PT; ++j) {
        const int g = j * BLOCK + tid;       // coalesced float4
        float4 a = yt4[g];
        float4 b = yp4[g];
        float4 rv;
        rv.x = fabsf(a.x - b.x); rv.y = fabsf(a.y - b.y);
        rv.z = fabsf(a.z - b.z); rv.w = fabsf(a.w - b.w);
        s_r[g] = rv;                         // ds_write_b128, contiguous
        rmax = fmaxf(rmax, fmaxf(fmaxf(rv.x, rv.y), fmaxf(rv.z, rv.w)));
    }
    rmax = wave64_max_dpp(rmax);
    if (lane == 0) s_wmax[wid] = rmax;
    #pragma unroll
    for (int i = 0; i < NBINS / BLOCK; ++i) s_hist[tid + i * BLOCK] = 0u;
    __syncthreads();                  // s_r + s_wmax visible, hist zeroed.
                                      // (also blocks store->load forwarding)
    rmax = fmaxf(fmaxf(s_wmax[0], s_wmax[1]), fmaxf(s_wmax[2], s_wmax[3]));
    rmax = fmaxf(rmax, 1e-8f);

    // ---- pass 2: histogram from LDS (count only; bin centers are proxy) ----
    const float hscale = (float)NBINS / rmax;
    #pragma unroll
    for (int j = 0; j < F4PT; ++j) {
        const float4 rv = s_r[j * BLOCK + tid];
        unsigned bx = min((unsigned)(rv.x * hscale), (unsigned)(NBINS - 1));
        unsigned by = min((unsigned)(rv.y * hscale), (unsigned)(NBINS - 1));
        unsigned bz = min((unsigned)(rv.z * hscale), (unsigned)(NBINS - 1));
        unsigned bw = min((unsigned)(rv.w * hscale), (unsigned)(NBINS - 1));
        atomicAdd(&s_hist[bx], 1u);
        atomicAdd(&s_hist[by], 1u);
        atomicAdd(&s_hist[bz], 1u);
        atomicAdd(&s_hist[bw], 1u);
    }
    __syncthreads();                          // histogram complete

    // ---- prefetch Lambda: in flight during the Newton solve; the
    //      pre-barrier vmcnt drain guarantees arrival by the next barrier ----
    const float4* lam4 = (const float4*)(Lambda + base);
    float4 lam[F4PT];
    #pragma unroll
    for (int j = 0; j < F4PT; ++j) lam[j] = lam4[j * BLOCK + tid];

    // ---- Newton on the 1024-bin histogram: wave 0 only ----
    if (wid == 0) {
        float nreg[BPL];                     // iteration-invariant bin counts
        #pragma unroll
        for (int k = 0; k < BPL; ++k) nreg[k] = (float)s_hist[lane + 64 * k];

        float eps = rmax / (logf(2.0f * (float)N_COLS) + 1e-8f);
        const float binw = rmax * (1.0f / (float)NBINS);
        const float sc2  = 0.5f / (float)N_COLS;   // 2^-14 exact
        for (int it = 0; it < 20; ++it) {
            const float inv_eps = __builtin_amdgcn_rcpf(fmaxf(eps, 1e-8f));
            const float d   = binw * inv_eps;       // per-bin u step
            const float d64 = 64.0f * d;            // per-k u step (this lane)
            float u  = ((float)lane + 0.5f) * d;
            float e  = __expf(u);                   // running exp(+u)
            float ei = __expf(-u);                  // running exp(-u)
            const float E  = __expf(d64);           // geometric ratios
            const float Ei = __expf(-d64);
            float fs = 0.0f, gs = 0.0f;     // sum n*(e-ei), sum n*(e+ei)*u
            #pragma unroll
            for (int k = 0; k < BPL; ++k) {
                const float n = nreg[k];
                fs = fmaf(n, e - ei, fs);
                gs = fmaf(n * (e + ei), u, gs);
                e *= E; ei *= Ei; u += d64;
            }
            fs = wave64_sum_dpp(fs);
            gs = wave64_sum_dpp(gs);
            float val  = fmaf(fs, sc2, -1.0f);          // mean(sinh)-1
            float grad = -(gs * sc2) * inv_eps;         // mean(cosh*(-u/eps))
            float delta = val * __builtin_amdgcn_rcpf(grad - 1e-8f);
            eps -= delta;
            if (fabsf(delta) <= 1e-5f * eps) break;     // wave-uniform
        }
        eps = fmaxf(eps, 1e-8f);
        const float beta = 1.0f / (eps + 1e-6f);
        const float um = beta * rmax;                   // qmax = sinh(beta*rmax)
        const float qmax = 0.5f * (__expf(um) - __expf(-um));
        if (lane == 0) {
            s_bcast[0] = beta;
            s_bcast[1] = 1.0f / (qmax + 1e-20f);
        }
    }
    __syncthreads();
    const float beta     = s_bcast[0];
    const float inv_qmax = s_bcast[1];

    // ---- epilogue: r from LDS, q=sinh(beta*r), EMA, nt-store, loss ----
    float* outw = out + 1 + base;   // 4B-aligned only -> scalar stores
                                    // (WRITE_SIZE proved HW coalesces them)
    float s_loss = 0.0f;
    #pragma unroll
    for (int j = 0; j < F4PT; ++j) {
        const int g = j * BLOCK + tid;
        const float4 rv = s_r[g];
        const float4 L  = lam[j];
        float rr[4] = {rv.x, rv.y, rv.z, rv.w};
        float LL[4] = {L.x, L.y, L.z, L.w};
        #pragma unroll
        for (int c = 0; c < 4; ++c) {
            float u  = beta * rr[c];
            float q  = 0.5f * (__expf(u) - __expf(-u));
            float lam_it = fmaf(0.9f, q * inv_qmax, 0.1f);  // PHI, 1-PHI
            float uL = fmaf(0.99f, LL[c], 0.1f * lam_it);   // GAMMA, ETA
            __builtin_nontemporal_store(uL, &outw[(size_t)g * 4 + c]);
            float t = uL * rr[c];
            s_loss = fmaf(t, t, s_loss);
        }
    }
    s_loss = wave64_sum_dpp(s_loss);
    if (lane == 0) s_part[wid] = s_loss;
    __syncthreads();
    if (tid == 0) {
        float tot = (s_part[0] + s_part[1]) + (s_part[2] + s_part[3]);
        atomicAdd(out, tot * inv_total);
    }
}

extern "C" void kernel_launch(void* const* d_in, const int* in_sizes, int n_in,
                              void* d_out, int out_size, void* d_ws, size_t ws_size,
                              hipStream_t stream) {
    const float* y_pred = (const float*)d_in[0];
    const float* y_true = (const float*)d_in[1];
    const float* Lambda = (const float*)d_in[2];
    float* out = (float*)d_out;

    const int total = in_sizes[0];            // B * N
    const int B = total / N_COLS;
    const float inv_total = 1.0f / (float)total;

    hipLaunchKernelGGL(zero_out_kernel, dim3(1), dim3(64), 0, stream, out);
    hipLaunchKernelGGL(custom_loss_kernel, dim3(B), dim3(BLOCK), 0, stream,
                       y_pred, y_true, Lambda, out, inv_total);
}